// Round 14
// baseline (222.717 us; speedup 1.0000x reference)
//
#include <hip/hip_runtime.h>

typedef short bf16x8 __attribute__((ext_vector_type(8)));
typedef float f32x4 __attribute__((ext_vector_type(4)));
typedef unsigned uint4v __attribute__((ext_vector_type(4)));

#define B_    8
#define L_    500
#define LP    512
#define H_    16
#define DK    64
#define DM    1024
#define NT    8      // attn: 512 / 64 keys per tile

static __device__ __forceinline__ unsigned short f2bf(float x) {
  unsigned u = __float_as_uint(x);
  u += 0x7fffu + ((u >> 16) & 1u);   // RNE
  return (unsigned short)(u >> 16);
}

static __device__ __forceinline__ unsigned cvtpk(float lo, float hi) {
  unsigned r;
  asm("v_cvt_pk_bf16_f32 %0, %1, %2" : "=v"(r) : "v"(lo), "v"(hi));
  return r;
}

static __device__ __forceinline__ void gload16(const void* g, void* l) {
  __builtin_amdgcn_global_load_lds(
      (const __attribute__((address_space(1))) void*)g,
      (__attribute__((address_space(3))) void*)l, 16, 0, 0);
}

static __device__ __forceinline__ f32x4 MF(bf16x8 a, bf16x8 b, f32x4 c) {
  return __builtin_amdgcn_mfma_f32_16x16x32_bf16(a, b, c, 0, 0, 0);
}

// ---------- prep: W (k,n) f32 -> Wt (n,k) bf16 (bx<256) + vt tail zero (bx>=256) ----------
__global__ __launch_bounds__(256) void conv_kernel(
    const float* __restrict__ wq, const float* __restrict__ wk,
    const float* __restrict__ wv,
    unsigned short* __restrict__ Wt, unsigned short* __restrict__ vt) {
  const int z = blockIdx.y;
  const int bx = blockIdx.x;
  const int tid = threadIdx.x;
  if (bx >= 256) {
    if (z == 0) {
      const int idx = (bx - 256) * 256 + tid;       // 0..8191 = bh*64 + d
      unsigned short* p = vt + (size_t)idx * LP + 496;
      const uint4 zz = {0u, 0u, 0u, 0u};
      *(uint4*)(p)     = zz;
      *(uint4*)(p + 8) = zz;
    }
    return;
  }
  const float* W = (z == 0) ? wq : (z == 1) ? wk : wv;
  const int k0 = (bx >> 4) * 64;
  const int n0 = (bx & 15) * 64;
  __shared__ float t[64][65];
  const int row = tid >> 2;
  const int cb  = (tid & 3) * 16;
#pragma unroll
  for (int s = 0; s < 4; ++s) {
    const float4 v = *(const float4*)(W + (size_t)(k0 + row) * DM + n0 + cb + s * 4);
    t[row][cb + s * 4 + 0] = v.x; t[row][cb + s * 4 + 1] = v.y;
    t[row][cb + s * 4 + 2] = v.z; t[row][cb + s * 4 + 3] = v.w;
  }
  __syncthreads();
  const int nr = tid >> 2;
  const int kb = (tid & 3) * 16;
#pragma unroll
  for (int s = 0; s < 2; ++s) {
    unsigned short o[8];
#pragma unroll
    for (int e = 0; e < 8; ++e) o[e] = f2bf(t[kb + s * 8 + e][nr]);
    uint4 pk;
    pk.x = (unsigned)o[0] | ((unsigned)o[1] << 16);
    pk.y = (unsigned)o[2] | ((unsigned)o[3] << 16);
    pk.z = (unsigned)o[4] | ((unsigned)o[5] << 16);
    pk.w = (unsigned)o[6] | ((unsigned)o[7] << 16);
    *(uint4*)(Wt + (size_t)z * DM * DM + (size_t)(n0 + nr) * DM + k0 + kb + s * 8) = pk;
  }
}

// ---------- fused conv+QKV GEMM: A read as f32 with 1-iter-lead reg pipeline,
//            B via gload_lds 3-ring (counted vmcnt); A ring-2 via ds_write ----------
__global__ __launch_bounds__(256) void gemm_qkv_kernel(
    const float* __restrict__ xq, const float* __restrict__ xk,
    const float* __restrict__ xv, const unsigned short* __restrict__ Wt,
    const float* __restrict__ bq, const float* __restrict__ bk,
    const float* __restrict__ bv,
    unsigned short* __restrict__ qo, unsigned short* __restrict__ ko,
    unsigned short* __restrict__ vo) {
  const int z = blockIdx.y;
  const float* Af = (z == 0) ? xq : (z == 1) ? xk : xv;
  const unsigned short* Bw = Wt + (size_t)z * DM * DM;
  const float* bias = (z == 0) ? bq : (z == 1) ? bk : bv;
  unsigned short* out = (z == 0) ? qo : (z == 1) ? ko : vo;

  const int bid = blockIdx.x;
  const int xg = bid & 7, y = bid >> 3;
  const int tm = xg + 8 * (y >> 3);           // 0..31
  const int tn = y & 7;                       // 0..7
  const int tid = threadIdx.x;
  const int lane = tid & 63, wid = tid >> 6;
  const int wr = wid >> 1, wc = wid & 1;
  const int lg = lane >> 4, lr = lane & 15;

  __shared__ __attribute__((aligned(16))) unsigned short sA[2][128 * 32];
  __shared__ __attribute__((aligned(16))) unsigned short sB[3][128 * 32];

  const int c0 = tid, c1 = tid + 256;
  const int ar0 = c0 >> 2, ak0 = (c0 & 3) * 8;
  const int ar1 = c1 >> 2, ak1 = (c1 & 3) * 8;
  const int am0 = tm * 128 + ar0, am1 = tm * 128 + ar1;
  const bool ok0 = am0 < 4000, ok1 = am1 < 4000;
  const float* fA0 = Af + (size_t)am0 * DM + ak0;
  const float* fA1 = Af + (size_t)am1 * DM + ak1;
  const unsigned short* Bb = Bw + (size_t)tn * 128 * DM;
  const unsigned short* gB0 = Bb + (size_t)ar0 * DM + ak0;
  const unsigned short* gB1 = Bb + (size_t)ar1 * DM + ak1;

  float4 r0, r1, r2, r3;
  const float4 fz = {0.f, 0.f, 0.f, 0.f};
  auto LOADA = [&](int t) {
    const int kn = t * 32;
    if (ok0) { r0 = *(const float4*)(fA0 + kn); r1 = *(const float4*)(fA0 + kn + 4); }
    else     { r0 = fz; r1 = fz; }
    if (ok1) { r2 = *(const float4*)(fA1 + kn); r3 = *(const float4*)(fA1 + kn + 4); }
    else     { r2 = fz; r3 = fz; }
  };
  auto WRITEA = [&](int buf) {
    uint4 w0, w1;
    w0.x = cvtpk(r0.x, r0.y); w0.y = cvtpk(r0.z, r0.w);
    w0.z = cvtpk(r1.x, r1.y); w0.w = cvtpk(r1.z, r1.w);
    w1.x = cvtpk(r2.x, r2.y); w1.y = cvtpk(r2.z, r2.w);
    w1.z = cvtpk(r3.x, r3.y); w1.w = cvtpk(r3.z, r3.w);
    *(uint4*)&sA[buf][c0 * 8] = w0;
    *(uint4*)&sA[buf][c1 * 8] = w1;
  };
  auto STAGEB = [&](int t) {
    const int buf = t % 3;
    const int kn = t * 32;
    gload16(gB0 + kn, &sB[buf][c0 * 8]);
    gload16(gB1 + kn, &sB[buf][c1 * 8]);
  };

  f32x4 acc[4][4];
#pragma unroll
  for (int i = 0; i < 4; ++i)
#pragma unroll
    for (int j = 0; j < 4; ++j) acc[i][j] = (f32x4){0.f, 0.f, 0.f, 0.f};

  // prologue: A(0) f32 -> regs; B(0),B(1) in flight; write A(0); A(1) f32 -> regs
  LOADA(0);
  STAGEB(0); STAGEB(1);
  WRITEA(0);          // implicit wait for A(0) f32
  LOADA(1);
  asm volatile("s_waitcnt vmcnt(6) lgkmcnt(0)" ::: "memory");  // B(0) landed; A(0) writes visible
  __builtin_amdgcn_s_barrier();
  __builtin_amdgcn_sched_barrier(0);

  for (int t = 0; t < 32; ++t) {
    if (t < 31) WRITEA((t + 1) & 1);        // consumes R = A(t+1); implicit vmcnt
    if (t < 30) { LOADA(t + 2); STAGEB(t + 2); }
    const int cb = t % 3;
    bf16x8 af[4], bfr[4];
#pragma unroll
    for (int s = 0; s < 4; ++s) {
      af[s]  = *(const bf16x8*)&sA[t & 1][(wr * 64 + s * 16 + lr) * 32 + lg * 8];
      bfr[s] = *(const bf16x8*)&sB[cb][(wc * 64 + s * 16 + lr) * 32 + lg * 8];
    }
#pragma unroll
    for (int i = 0; i < 4; ++i)
#pragma unroll
      for (int j = 0; j < 4; ++j)
        acc[i][j] = MF(af[i], bfr[j], acc[i][j]);
    if (t < 31) {
      if (t < 30) asm volatile("s_waitcnt vmcnt(6) lgkmcnt(0)" ::: "memory");
      else        asm volatile("s_waitcnt vmcnt(0) lgkmcnt(0)" ::: "memory");
      __builtin_amdgcn_s_barrier();
      __builtin_amdgcn_sched_barrier(0);
    }
  }

  const int nbase = tn * 128 + wc * 64 + lr;
  float bias4[4];
#pragma unroll
  for (int ns = 0; ns < 4; ++ns) bias4[ns] = bias[nbase + ns * 16];

  if (z == 2) {
    // V^T epilogue via per-wave LDS transpose. Dead after t=31 (reads sA[1], sB[1]):
    // sA[0], sB[0], sB[2]. Four [16][72]=1152-short regions (wave1 at sA[0]+2048).
    unsigned short* T = (wid == 0) ? &sA[0][0] : (wid == 1) ? &sA[0][2048]
                      : (wid == 2) ? &sB[0][0] : &sB[2][0];
    const int hh = tn * 2 + wc;
    const int m0w = tm * 128 + wr * 64;
    const int li = lane & 15;                 // this lane's l-chunk of 4
    const int m = m0w + li * 4;
    const unsigned batch = (unsigned)m / 500u;
    const int lrow = m - (int)batch * 500;    // chunk never straddles 500 (500 % 4 == 0)
    unsigned short* ob = out + (((size_t)batch * H_ + hh) * DK) * LP + lrow;
    const bool ok = (m < 4000);
#pragma unroll
    for (int ns = 0; ns < 4; ++ns) {          // 16 d-rows per pass
#pragma unroll
      for (int ms = 0; ms < 4; ++ms) {
        uint2 pk;
        pk.x = (unsigned)f2bf(acc[ms][ns][0] + bias4[ns]) |
               ((unsigned)f2bf(acc[ms][ns][1] + bias4[ns]) << 16);
        pk.y = (unsigned)f2bf(acc[ms][ns][2] + bias4[ns]) |
               ((unsigned)f2bf(acc[ms][ns][3] + bias4[ns]) << 16);
        *(uint2*)&T[lr * 72 + ms * 16 + lg * 4] = pk;
      }
      asm volatile("s_waitcnt lgkmcnt(0)" ::: "memory");
      __builtin_amdgcn_sched_barrier(0);
      if (ok) {
#pragma unroll
        for (int it = 0; it < 4; ++it) {
          const int dl = it * 4 + lg;          // 0..15
          const uint2 v = *(const uint2*)&T[dl * 72 + li * 4];
          *(uint2*)(ob + (size_t)(ns * 16 + dl) * LP) = v;
        }
      }
      asm volatile("s_waitcnt lgkmcnt(0)" ::: "memory");
      __builtin_amdgcn_sched_barrier(0);
    }
  } else {
#pragma unroll
    for (int ms = 0; ms < 4; ++ms) {
#pragma unroll
      for (int r = 0; r < 4; ++r) {
        const int m = tm * 128 + wr * 64 + ms * 16 + lg * 4 + r;
        if (m < 4000) {
          const unsigned batch = (unsigned)m / 500u;
          const int lrow = m - (int)batch * 500;
#pragma unroll
          for (int ns = 0; ns < 4; ++ns) {
            const int n = nbase + ns * 16;
            const int hh = n >> 6, d = n & 63;
            out[(((size_t)batch * H_ + hh) * LP + lrow) * DK + d] =
                f2bf(acc[ms][ns][r] + bias4[ns]);
          }
        }
      }
    }
  }
}

// ---------- flash attention: QBLK=128, 8 waves, staged K/V, sigma-permuted QK^T,
//            P entirely in registers ----------
__global__ __launch_bounds__(512, 2) void attn_kernel(
    const unsigned short* __restrict__ q, const unsigned short* __restrict__ k,
    const unsigned short* __restrict__ vt, const float* __restrict__ rel,
    float* __restrict__ out) {
  const int id = blockIdx.x;           // XCD = id%8 = bh%8 -> per-XCD K/V L2 residency
  const int bh = id & 127, qc = id >> 7;   // qc 0..3, 128 q-rows each
  const int b = bh >> 4, h = bh & 15;
  const int tid = threadIdx.x;
  const int lane = tid & 63, wid = tid >> 6;    // 8 waves
  const int lg = lane >> 4, lr = lane & 15;

  __shared__ unsigned short kt[2][2][64][32];   // [buf][dhalf][key][d&31]
  __shared__ unsigned short vtt[2][2][64][32];  // [buf][keyhalf][d][key&31]
  __shared__ float relb[640];

  const float LOG2E = 1.44269504f;
  const float SC = 0.125f * LOG2E;
  const int rbase = qc * 128 - 12;
  for (int i = tid; i < 639; i += 512) {
    int idx = rbase + i;
    idx = idx < 0 ? 0 : (idx > 998 ? 998 : idx);
    relb[i] = rel[h * 999 + idx] * LOG2E;
  }

  const int qrow = qc * 128 + wid * 16 + lr;
  const unsigned short* qp = q + ((size_t)bh * LP + qrow) * DK + lg * 8;
  const bf16x8 qf0 = *(const bf16x8*)qp;
  const bf16x8 qf1 = *(const bf16x8*)(qp + 32);

  const int kj = tid >> 3, dcs = (tid & 7) * 8;
  const unsigned short* kgp = k + ((size_t)bh * LP + kj) * DK + dcs;
  unsigned short* kls = &kt[0][dcs >> 5][kj][dcs & 31];
  const int vd = tid >> 3, vkg = (tid & 7) * 8;
  const unsigned short* vgp = vt + ((size_t)bh * DK + vd) * LP + vkg;
  unsigned short* vls = &vtt[0][vkg >> 5][vd][vkg & 31];

  const int sig0 = 8 * (lr >> 2) + (lr & 3);   // sigma base
  const int qin = wid * 16 + lr;               // 0..127

  f32x4 o[4];
#pragma unroll
  for (int d = 0; d < 4; ++d) o[d] = (f32x4){0.f, 0.f, 0.f, 0.f};
  float mrun = -1e30f, lrun = 0.f;

  uint4 ka0 = *(const uint4*)(kgp);
  uint4 va0 = *(const uint4*)(vgp);

  for (int t = 0; t < NT; ++t) {
    const int buf = t & 1;
    *(uint4*)(kls + buf * 4096) = ka0;
    *(uint4*)(vls + buf * 4096) = va0;
    __syncthreads();

    if (t < NT - 1) {
      ka0 = *(const uint4*)(kgp + (size_t)(t + 1) * 64 * DK);
      va0 = *(const uint4*)(vgp + (t + 1) * 64);
    }

    f32x4 s[2][2];
#pragma unroll
    for (int kc = 0; kc < 2; ++kc)
#pragma unroll
      for (int hf = 0; hf < 2; ++hf) {
        const int sg = kc * 32 + hf * 4 + sig0;
        const bf16x8 a0 = *(const bf16x8*)&kt[buf][0][sg][lg * 8];
        const bf16x8 a1 = *(const bf16x8*)&kt[buf][1][sg][lg * 8];
        f32x4 ss = (f32x4){0.f, 0.f, 0.f, 0.f};
        ss = __builtin_amdgcn_mfma_f32_16x16x32_bf16(a0, qf0, ss, 0, 0, 0);
        ss = __builtin_amdgcn_mfma_f32_16x16x32_bf16(a1, qf1, ss, 0, 0, 0);
        s[kc][hf] = ss;
      }

    float sc[2][2][4];
#pragma unroll
    for (int kc = 0; kc < 2; ++kc)
#pragma unroll
      for (int hf = 0; hf < 2; ++hf) {
        const int bidx = qin - (t * 64 + kc * 32 + 8 * lg + 4 * hf) + 511;
#pragma unroll
        for (int r = 0; r < 4; ++r)
          sc[kc][hf][r] = s[kc][hf][r] * SC + relb[bidx - r];
      }
    if (t == NT - 1) {
#pragma unroll
      for (int hf = 0; hf < 2; ++hf)
#pragma unroll
        for (int r = 0; r < 4; ++r)
          if (8 * lg + 4 * hf + r >= 20) sc[1][hf][r] = -1e30f;
    }

    float m0 = fmaxf(fmaxf(sc[0][0][0], sc[0][0][1]), fmaxf(sc[0][0][2], sc[0][0][3]));
    float m1 = fmaxf(fmaxf(sc[0][1][0], sc[0][1][1]), fmaxf(sc[0][1][2], sc[0][1][3]));
    float m2 = fmaxf(fmaxf(sc[1][0][0], sc[1][0][1]), fmaxf(sc[1][0][2], sc[1][0][3]));
    float m3 = fmaxf(fmaxf(sc[1][1][0], sc[1][1][1]), fmaxf(sc[1][1][2], sc[1][1][3]));
    const float mloc = fmaxf(fmaxf(m0, m1), fmaxf(m2, m3));
    if (!__all(mloc - mrun <= 11.5f)) {
      float mx = fmaxf(mloc, mrun);
      mx = fmaxf(mx, __shfl_xor(mx, 16));
      mx = fmaxf(mx, __shfl_xor(mx, 32));
      const float alpha = exp2f(mrun - mx);
      mrun = mx;
      lrun *= alpha;
#pragma unroll
      for (int d = 0; d < 4; ++d) {
        o[d][0] *= alpha; o[d][1] *= alpha; o[d][2] *= alpha; o[d][3] *= alpha;
      }
    }

    float rs = 0.f;
    unsigned pw[2][4];
#pragma unroll
    for (int kc = 0; kc < 2; ++kc)
#pragma unroll
      for (int hf = 0; hf < 2; ++hf) {
        float p0 = exp2f(sc[kc][hf][0] - mrun);
        float p1 = exp2f(sc[kc][hf][1] - mrun);
        float p2 = exp2f(sc[kc][hf][2] - mrun);
        float p3 = exp2f(sc[kc][hf][3] - mrun);
        rs += (p0 + p1) + (p2 + p3);
        pw[kc][hf * 2 + 0] = cvtpk(p0, p1);
        pw[kc][hf * 2 + 1] = cvtpk(p2, p3);
      }
    rs += __shfl_xor(rs, 16);
    rs += __shfl_xor(rs, 32);
    lrun += rs;

#pragma unroll
    for (int kc = 0; kc < 2; ++kc) {
      union { uint4v u; bf16x8 v; } cv;
      cv.u = (uint4v){pw[kc][0], pw[kc][1], pw[kc][2], pw[kc][3]};
      const bf16x8 pf = cv.v;
#pragma unroll
      for (int db = 0; db < 4; ++db) {
        const bf16x8 vf = *(const bf16x8*)&vtt[buf][kc][db * 16 + lr][lg * 8];
        o[db] = __builtin_amdgcn_mfma_f32_16x16x32_bf16(vf, pf, o[db], 0, 0, 0);
      }
    }
  }

  if (qrow < L_) {
    const float inv = 1.0f / lrun;
    float* op = out + ((size_t)b * L_ + qrow) * DM + h * DK + lg * 4;
#pragma unroll
    for (int db = 0; db < 4; ++db) {
      float4 v;
      v.x = o[db][0] * inv; v.y = o[db][1] * inv;
      v.z = o[db][2] * inv; v.w = o[db][3] * inv;
      *(float4*)(op + db * 16) = v;
    }
  }
}

extern "C" void kernel_launch(void* const* d_in, const int* in_sizes, int n_in,
                              void* d_out, int out_size, void* d_ws, size_t ws_size,
                              hipStream_t stream) {
  const float* iq  = (const float*)d_in[0];
  const float* ik  = (const float*)d_in[1];
  const float* iv  = (const float*)d_in[2];
  const float* wq  = (const float*)d_in[3];
  const float* bq  = (const float*)d_in[4];
  const float* wk  = (const float*)d_in[5];
  const float* bk  = (const float*)d_in[6];
  const float* wv  = (const float*)d_in[7];
  const float* bv  = (const float*)d_in[8];
  const float* rel = (const float*)d_in[9];
  float* out = (float*)d_out;

  char* w = (char*)d_ws;
  unsigned short* Wt  = (unsigned short*)(w + 25165824);      // [3][1024][1024] bf16 (n,k)
  unsigned short* qb  = (unsigned short*)(w + 31457280);      // [128][512][64] bf16
  unsigned short* kb  = (unsigned short*)(w + 39845888);
  unsigned short* vtb = (unsigned short*)(w + 48234496);      // [128][64][512] bf16 (V^T)

  conv_kernel<<<dim3(288, 3), 256, 0, stream>>>(wq, wk, wv, Wt, vtb);
  gemm_qkv_kernel<<<dim3(256, 3), 256, 0, stream>>>(iq, ik, iv, Wt, bq, bk, bv, qb, kb, vtb);
  attn_kernel<<<512, 512, 0, stream>>>(qb, kb, vtb, rel, out);
}

// Round 15
// 83.363 us; speedup vs baseline: 2.6717x; 2.6717x over previous
//
#include <hip/hip_runtime.h>

typedef short bf16x8 __attribute__((ext_vector_type(8)));
typedef float f32x4 __attribute__((ext_vector_type(4)));
typedef unsigned uint4v __attribute__((ext_vector_type(4)));

#define B_    8
#define L_    500
#define LP    512
#define H_    16
#define DK    64
#define DM    1024
#define MP    4096
#define NT    8      // attn: 512 / 64 keys per tile

static __device__ __forceinline__ unsigned short f2bf(float x) {
  unsigned u = __float_as_uint(x);
  u += 0x7fffu + ((u >> 16) & 1u);   // RNE
  return (unsigned short)(u >> 16);
}

static __device__ __forceinline__ unsigned cvtpk(float lo, float hi) {
  unsigned r;
  asm("v_cvt_pk_bf16_f32 %0, %1, %2" : "=v"(r) : "v"(lo), "v"(hi));
  return r;
}

static __device__ __forceinline__ void gload16(const void* g, void* l) {
  __builtin_amdgcn_global_load_lds(
      (const __attribute__((address_space(1))) void*)g,
      (__attribute__((address_space(3))) void*)l, 16, 0, 0);
}

static __device__ __forceinline__ f32x4 MF(bf16x8 a, bf16x8 b, f32x4 c) {
  return __builtin_amdgcn_mfma_f32_16x16x32_bf16(a, b, c, 0, 0, 0);
}

// ---------- merged prep: conv_x (bx<2048) + conv_w (2048<=bx<2304) + vt tail zero ----------
__global__ __launch_bounds__(256) void conv_kernel(
    const float* __restrict__ iq, const float* __restrict__ ik,
    const float* __restrict__ iv,
    const float* __restrict__ wq, const float* __restrict__ wk,
    const float* __restrict__ wv,
    unsigned short* __restrict__ X, unsigned short* __restrict__ Wt,
    unsigned short* __restrict__ vt) {
  const int z = blockIdx.y;
  const int bx = blockIdx.x;
  const int tid = threadIdx.x;
  if (bx < 2048) {
    const float* src = (z == 0) ? iq : (z == 1) ? ik : iv;
    const size_t off = ((size_t)bx * 256 + tid) * 8;
    const int m = (int)(off >> 10);
    unsigned short o[8];
    if (m < 4000) {
      const float4 a = *(const float4*)(src + off);
      const float4 b = *(const float4*)(src + off + 4);
      o[0]=f2bf(a.x); o[1]=f2bf(a.y); o[2]=f2bf(a.z); o[3]=f2bf(a.w);
      o[4]=f2bf(b.x); o[5]=f2bf(b.y); o[6]=f2bf(b.z); o[7]=f2bf(b.w);
    } else {
#pragma unroll
      for (int i = 0; i < 8; ++i) o[i] = 0;
    }
    uint4 pk;
    pk.x = (unsigned)o[0] | ((unsigned)o[1] << 16);
    pk.y = (unsigned)o[2] | ((unsigned)o[3] << 16);
    pk.z = (unsigned)o[4] | ((unsigned)o[5] << 16);
    pk.w = (unsigned)o[6] | ((unsigned)o[7] << 16);
    *(uint4*)(X + (size_t)z * MP * DM + off) = pk;
    return;
  }
  if (bx >= 2304) {
    // zero V^T rows l in [496,512) for all (bh, d); gemm later overwrites 496..499
    if (z == 0) {
      const int idx = (bx - 2304) * 256 + tid;      // 0..8191 = bh*64 + d
      unsigned short* p = vt + (size_t)idx * LP + 496;
      const uint4 zz = {0u, 0u, 0u, 0u};
      *(uint4*)(p)     = zz;
      *(uint4*)(p + 8) = zz;
    }
    return;
  }
  const int bw = bx - 2048;
  const float* W = (z == 0) ? wq : (z == 1) ? wk : wv;
  const int k0 = (bw >> 4) * 64;
  const int n0 = (bw & 15) * 64;
  __shared__ float t[64][65];
  const int row = tid >> 2;
  const int cb  = (tid & 3) * 16;
#pragma unroll
  for (int s = 0; s < 4; ++s) {
    const float4 v = *(const float4*)(W + (size_t)(k0 + row) * DM + n0 + cb + s * 4);
    t[row][cb + s * 4 + 0] = v.x; t[row][cb + s * 4 + 1] = v.y;
    t[row][cb + s * 4 + 2] = v.z; t[row][cb + s * 4 + 3] = v.w;
  }
  __syncthreads();
  const int nr = tid >> 2;
  const int kb = (tid & 3) * 16;
#pragma unroll
  for (int s = 0; s < 2; ++s) {
    unsigned short o[8];
#pragma unroll
    for (int e = 0; e < 8; ++e) o[e] = f2bf(t[kb + s * 8 + e][nr]);
    uint4 pk;
    pk.x = (unsigned)o[0] | ((unsigned)o[1] << 16);
    pk.y = (unsigned)o[2] | ((unsigned)o[3] << 16);
    pk.z = (unsigned)o[4] | ((unsigned)o[5] << 16);
    pk.w = (unsigned)o[6] | ((unsigned)o[7] << 16);
    *(uint4*)(Wt + (size_t)z * DM * DM + (size_t)(n0 + nr) * DM + k0 + kb + s * 8) = pk;
  }
}

// ---------- fused QKV projection GEMM (m97 structure + 3-buffer counted-vmcnt ring) ----------
// z==0/1 write q/k in [b][h][l(512)][64]; z==2 writes V^T [b*16+h][d][l(512)] via
// per-wave LDS transpose in TWO 32-d halves (fits the 8KB dead buffers).
__global__ __launch_bounds__(256) void gemm_qkv_kernel(
    const unsigned short* __restrict__ X, const unsigned short* __restrict__ Wt,
    const float* __restrict__ bq, const float* __restrict__ bk,
    const float* __restrict__ bv,
    unsigned short* __restrict__ qo, unsigned short* __restrict__ ko,
    unsigned short* __restrict__ vo) {
  const int z = blockIdx.y;
  const unsigned short* A  = X  + (size_t)z * MP * DM;
  const unsigned short* Bw = Wt + (size_t)z * DM * DM;
  const float* bias = (z == 0) ? bq : (z == 1) ? bk : bv;
  unsigned short* out = (z == 0) ? qo : (z == 1) ? ko : vo;

  const int bid = blockIdx.x;
  const int xg = bid & 7, y = bid >> 3;
  const int tm = xg + 8 * (y >> 3);           // 0..31
  const int tn = y & 7;                       // 0..7
  const int tid = threadIdx.x;
  const int lane = tid & 63, wid = tid >> 6;
  const int wr = wid >> 1, wc = wid & 1;
  const int lg = lane >> 4, lr = lane & 15;

  __shared__ __attribute__((aligned(16))) unsigned short sA[3][128 * 32];
  __shared__ __attribute__((aligned(16))) unsigned short sB[3][128 * 32];

  const int c0 = tid, c1 = tid + 256;
  const int ar0 = c0 >> 2, ak0 = (c0 & 3) * 8;
  const int ar1 = c1 >> 2, ak1 = (c1 & 3) * 8;
  const unsigned short* Ab = A  + (size_t)tm * 128 * DM;
  const unsigned short* Bb = Bw + (size_t)tn * 128 * DM;

  auto STAGE = [&](int t) {
    const int buf = t % 3;
    const int kn = t * 32;
    gload16(Ab + (size_t)ar0 * DM + kn + ak0, &sA[buf][c0 * 8]);
    gload16(Ab + (size_t)ar1 * DM + kn + ak1, &sA[buf][c1 * 8]);
    gload16(Bb + (size_t)ar0 * DM + kn + ak0, &sB[buf][c0 * 8]);
    gload16(Bb + (size_t)ar1 * DM + kn + ak1, &sB[buf][c1 * 8]);
  };

  f32x4 acc[4][4];
#pragma unroll
  for (int i = 0; i < 4; ++i)
#pragma unroll
    for (int j = 0; j < 4; ++j) acc[i][j] = (f32x4){0.f, 0.f, 0.f, 0.f};

  // prologue: tiles 0,1 in flight; wait tile0 (leave tile1's 4 loads in flight)
  STAGE(0); STAGE(1);
  asm volatile("s_waitcnt vmcnt(4)" ::: "memory");
  __builtin_amdgcn_s_barrier();
  __builtin_amdgcn_sched_barrier(0);

  for (int t = 0; t < 32; ++t) {
    if (t < 30) STAGE(t + 2);               // issue into buf (t+2)%3 (last read at t-1)
    const int cb = t % 3;
    bf16x8 af[4], bfr[4];
#pragma unroll
    for (int s = 0; s < 4; ++s) {
      af[s]  = *(const bf16x8*)&sA[cb][(wr * 64 + s * 16 + lr) * 32 + lg * 8];
      bfr[s] = *(const bf16x8*)&sB[cb][(wc * 64 + s * 16 + lr) * 32 + lg * 8];
    }
#pragma unroll
    for (int i = 0; i < 4; ++i)
#pragma unroll
      for (int j = 0; j < 4; ++j)
        acc[i][j] = MF(af[i], bfr[j], acc[i][j]);
    if (t < 31) {
      if (t < 30) asm volatile("s_waitcnt vmcnt(4)" ::: "memory");  // t+1 landed, t+2 in flight
      else        asm volatile("s_waitcnt vmcnt(0)" ::: "memory");  // tail: t=30 waits tile31
      __builtin_amdgcn_s_barrier();
      __builtin_amdgcn_sched_barrier(0);
    }
  }

  const int nbase = tn * 128 + wc * 64 + lr;
  float bias4[4];
#pragma unroll
  for (int ns = 0; ns < 4; ++ns) bias4[ns] = bias[nbase + ns * 16];

  if (z == 2) {
    // per-wave transpose buffer (8KB, dead after t=30 barrier; t=31 uses only buf 1).
    // Two passes of 32 d-rows each: [32][72] = 2304 shorts << 4096.
    unsigned short* T = (wid == 0) ? &sA[0][0] : (wid == 1) ? &sA[2][0]
                      : (wid == 2) ? &sB[0][0] : &sB[2][0];
    const int hh = tn * 2 + wc;
    const int m0w = tm * 128 + wr * 64;
    const int li = lane & 15;                 // this lane's l-chunk of 4
    const int m = m0w + li * 4;
    const unsigned batch = (unsigned)m / 500u;
    const int lrow = m - (int)batch * 500;    // chunk never straddles 500 (500 % 4 == 0)
    unsigned short* ob = out + (((size_t)batch * H_ + hh) * DK) * LP + lrow;
    const bool ok = (m < 4000);
#pragma unroll
    for (int half = 0; half < 2; ++half) {
      // write phase: d-local = nsl*16 + lr (0..31), l-local = ms*16 + lg*4 (+0..3)
#pragma unroll
      for (int ms = 0; ms < 4; ++ms)
#pragma unroll
        for (int nsl = 0; nsl < 2; ++nsl) {
          const int ns = half * 2 + nsl;
          uint2 pk;
          pk.x = (unsigned)f2bf(acc[ms][ns][0] + bias4[ns]) |
                 ((unsigned)f2bf(acc[ms][ns][1] + bias4[ns]) << 16);
          pk.y = (unsigned)f2bf(acc[ms][ns][2] + bias4[ns]) |
                 ((unsigned)f2bf(acc[ms][ns][3] + bias4[ns]) << 16);
          *(uint2*)&T[(nsl * 16 + lr) * 72 + ms * 16 + lg * 4] = pk;
        }
      asm volatile("s_waitcnt lgkmcnt(0)" ::: "memory");   // writes visible in-wave
      __builtin_amdgcn_sched_barrier(0);
      // read+store phase: lane covers d-local = it*4 + lg, its own l-chunk li*4
      if (ok) {
#pragma unroll
        for (int it = 0; it < 8; ++it) {
          const int dl = it * 4 + lg;          // 0..31
          const uint2 v = *(const uint2*)&T[dl * 72 + li * 4];
          *(uint2*)(ob + (size_t)(half * 32 + dl) * LP) = v;
        }
      }
      asm volatile("s_waitcnt lgkmcnt(0)" ::: "memory");   // reads done before reuse
      __builtin_amdgcn_sched_barrier(0);
    }
  } else {
#pragma unroll
    for (int ms = 0; ms < 4; ++ms) {
#pragma unroll
      for (int r = 0; r < 4; ++r) {
        const int m = tm * 128 + wr * 64 + ms * 16 + lg * 4 + r;
        if (m < 4000) {
          const unsigned batch = (unsigned)m / 500u;
          const int lrow = m - (int)batch * 500;
#pragma unroll
          for (int ns = 0; ns < 4; ++ns) {
            const int n = nbase + ns * 16;
            const int hh = n >> 6, d = n & 63;
            out[(((size_t)batch * H_ + hh) * LP + lrow) * DK + d] =
                f2bf(acc[ms][ns][r] + bias4[ns]);
          }
        }
      }
    }
  }
}

// ---------- flash attention: QBLK=128, 8 waves, staged K/V, sigma-permuted QK^T,
//            P entirely in registers ----------
__global__ __launch_bounds__(512, 2) void attn_kernel(
    const unsigned short* __restrict__ q, const unsigned short* __restrict__ k,
    const unsigned short* __restrict__ vt, const float* __restrict__ rel,
    float* __restrict__ out) {
  const int id = blockIdx.x;           // XCD = id%8 = bh%8 -> per-XCD K/V L2 residency
  const int bh = id & 127, qc = id >> 7;   // qc 0..3, 128 q-rows each
  const int b = bh >> 4, h = bh & 15;
  const int tid = threadIdx.x;
  const int lane = tid & 63, wid = tid >> 6;    // 8 waves
  const int lg = lane >> 4, lr = lane & 15;

  __shared__ unsigned short kt[2][2][64][32];   // [buf][dhalf][key][d&31]
  __shared__ unsigned short vtt[2][2][64][32];  // [buf][keyhalf][d][key&31]
  __shared__ float relb[640];

  const float LOG2E = 1.44269504f;
  const float SC = 0.125f * LOG2E;
  const int rbase = qc * 128 - 12;
  for (int i = tid; i < 639; i += 512) {
    int idx = rbase + i;
    idx = idx < 0 ? 0 : (idx > 998 ? 998 : idx);
    relb[i] = rel[h * 999 + idx] * LOG2E;
  }

  const int qrow = qc * 128 + wid * 16 + lr;
  const unsigned short* qp = q + ((size_t)bh * LP + qrow) * DK + lg * 8;
  const bf16x8 qf0 = *(const bf16x8*)qp;
  const bf16x8 qf1 = *(const bf16x8*)(qp + 32);

  const int kj = tid >> 3, dcs = (tid & 7) * 8;
  const unsigned short* kgp = k + ((size_t)bh * LP + kj) * DK + dcs;
  unsigned short* kls = &kt[0][dcs >> 5][kj][dcs & 31];
  const int vd = tid >> 3, vkg = (tid & 7) * 8;
  const unsigned short* vgp = vt + ((size_t)bh * DK + vd) * LP + vkg;
  unsigned short* vls = &vtt[0][vkg >> 5][vd][vkg & 31];

  const int sig0 = 8 * (lr >> 2) + (lr & 3);   // sigma base
  const int qin = wid * 16 + lr;               // 0..127

  f32x4 o[4];
#pragma unroll
  for (int d = 0; d < 4; ++d) o[d] = (f32x4){0.f, 0.f, 0.f, 0.f};
  float mrun = -1e30f, lrun = 0.f;

  uint4 ka0 = *(const uint4*)(kgp);
  uint4 va0 = *(const uint4*)(vgp);

  for (int t = 0; t < NT; ++t) {
    const int buf = t & 1;
    *(uint4*)(kls + buf * 4096) = ka0;
    *(uint4*)(vls + buf * 4096) = va0;
    __syncthreads();

    if (t < NT - 1) {
      ka0 = *(const uint4*)(kgp + (size_t)(t + 1) * 64 * DK);
      va0 = *(const uint4*)(vgp + (t + 1) * 64);
    }

    f32x4 s[2][2];
#pragma unroll
    for (int kc = 0; kc < 2; ++kc)
#pragma unroll
      for (int hf = 0; hf < 2; ++hf) {
        const int sg = kc * 32 + hf * 4 + sig0;
        const bf16x8 a0 = *(const bf16x8*)&kt[buf][0][sg][lg * 8];
        const bf16x8 a1 = *(const bf16x8*)&kt[buf][1][sg][lg * 8];
        f32x4 ss = (f32x4){0.f, 0.f, 0.f, 0.f};
        ss = __builtin_amdgcn_mfma_f32_16x16x32_bf16(a0, qf0, ss, 0, 0, 0);
        ss = __builtin_amdgcn_mfma_f32_16x16x32_bf16(a1, qf1, ss, 0, 0, 0);
        s[kc][hf] = ss;
      }

    float sc[2][2][4];
#pragma unroll
    for (int kc = 0; kc < 2; ++kc)
#pragma unroll
      for (int hf = 0; hf < 2; ++hf) {
        const int bidx = qin - (t * 64 + kc * 32 + 8 * lg + 4 * hf) + 511;
#pragma unroll
        for (int r = 0; r < 4; ++r)
          sc[kc][hf][r] = s[kc][hf][r] * SC + relb[bidx - r];
      }
    if (t == NT - 1) {
#pragma unroll
      for (int hf = 0; hf < 2; ++hf)
#pragma unroll
        for (int r = 0; r < 4; ++r)
          if (8 * lg + 4 * hf + r >= 20) sc[1][hf][r] = -1e30f;
    }

    float m0 = fmaxf(fmaxf(sc[0][0][0], sc[0][0][1]), fmaxf(sc[0][0][2], sc[0][0][3]));
    float m1 = fmaxf(fmaxf(sc[0][1][0], sc[0][1][1]), fmaxf(sc[0][1][2], sc[0][1][3]));
    float m2 = fmaxf(fmaxf(sc[1][0][0], sc[1][0][1]), fmaxf(sc[1][0][2], sc[1][0][3]));
    float m3 = fmaxf(fmaxf(sc[1][1][0], sc[1][1][1]), fmaxf(sc[1][1][2], sc[1][1][3]));
    const float mloc = fmaxf(fmaxf(m0, m1), fmaxf(m2, m3));
    if (!__all(mloc - mrun <= 11.5f)) {
      float mx = fmaxf(mloc, mrun);
      mx = fmaxf(mx, __shfl_xor(mx, 16));
      mx = fmaxf(mx, __shfl_xor(mx, 32));
      const float alpha = exp2f(mrun - mx);
      mrun = mx;
      lrun *= alpha;
#pragma unroll
      for (int d = 0; d < 4; ++d) {
        o[d][0] *= alpha; o[d][1] *= alpha; o[d][2] *= alpha; o[d][3] *= alpha;
      }
    }

    float rs = 0.f;
    unsigned pw[2][4];
#pragma unroll
    for (int kc = 0; kc < 2; ++kc)
#pragma unroll
      for (int hf = 0; hf < 2; ++hf) {
        float p0 = exp2f(sc[kc][hf][0] - mrun);
        float p1 = exp2f(sc[kc][hf][1] - mrun);
        float p2 = exp2f(sc[kc][hf][2] - mrun);
        float p3 = exp2f(sc[kc][hf][3] - mrun);
        rs += (p0 + p1) + (p2 + p3);
        pw[kc][hf * 2 + 0] = cvtpk(p0, p1);
        pw[kc][hf * 2 + 1] = cvtpk(p2, p3);
      }
    rs += __shfl_xor(rs, 16);
    rs += __shfl_xor(rs, 32);
    lrun += rs;

#pragma unroll
    for (int kc = 0; kc < 2; ++kc) {
      union { uint4v u; bf16x8 v; } cv;
      cv.u = (uint4v){pw[kc][0], pw[kc][1], pw[kc][2], pw[kc][3]};
      const bf16x8 pf = cv.v;
#pragma unroll
      for (int db = 0; db < 4; ++db) {
        const bf16x8 vf = *(const bf16x8*)&vtt[buf][kc][db * 16 + lr][lg * 8];
        o[db] = __builtin_amdgcn_mfma_f32_16x16x32_bf16(vf, pf, o[db], 0, 0, 0);
      }
    }
  }

  if (qrow < L_) {
    const float inv = 1.0f / lrun;
    float* op = out + ((size_t)b * L_ + qrow) * DM + h * DK + lg * 4;
#pragma unroll
    for (int db = 0; db < 4; ++db) {
      float4 v;
      v.x = o[db][0] * inv; v.y = o[db][1] * inv;
      v.z = o[db][2] * inv; v.w = o[db][3] * inv;
      *(float4*)(op + db * 16) = v;
    }
  }
}

extern "C" void kernel_launch(void* const* d_in, const int* in_sizes, int n_in,
                              void* d_out, int out_size, void* d_ws, size_t ws_size,
                              hipStream_t stream) {
  const float* iq  = (const float*)d_in[0];
  const float* ik  = (const float*)d_in[1];
  const float* iv  = (const float*)d_in[2];
  const float* wq  = (const float*)d_in[3];
  const float* bq  = (const float*)d_in[4];
  const float* wk  = (const float*)d_in[5];
  const float* bk  = (const float*)d_in[6];
  const float* wv  = (const float*)d_in[7];
  const float* bv  = (const float*)d_in[8];
  const float* rel = (const float*)d_in[9];
  float* out = (float*)d_out;

  char* w = (char*)d_ws;
  unsigned short* X   = (unsigned short*)(w);                 // [3][4096][1024] bf16
  unsigned short* Wt  = (unsigned short*)(w + 25165824);      // [3][1024][1024] bf16 (n,k)
  unsigned short* qb  = (unsigned short*)(w + 31457280);      // [128][512][64] bf16
  unsigned short* kb  = (unsigned short*)(w + 39845888);
  unsigned short* vtb = (unsigned short*)(w + 48234496);      // [128][64][512] bf16 (V^T)

  conv_kernel<<<dim3(2336, 3), 256, 0, stream>>>(iq, ik, iv, wq, wk, wv, X, Wt, vtb);
  gemm_qkv_kernel<<<dim3(256, 3), 256, 0, stream>>>(X, Wt, bq, bk, bv, qb, kb, vtb);
  attn_kernel<<<512, 512, 0, stream>>>(qb, kb, vtb, rel, out);
}

// Round 16
// 77.775 us; speedup vs baseline: 2.8636x; 1.0719x over previous
//
#include <hip/hip_runtime.h>

typedef short bf16x8 __attribute__((ext_vector_type(8)));
typedef float f32x4 __attribute__((ext_vector_type(4)));
typedef unsigned uint4v __attribute__((ext_vector_type(4)));

#define B_    8
#define L_    500
#define LP    512
#define H_    16
#define DK    64
#define DM    1024
#define MP    4096
#define NT    8      // attn: 512 / 64 keys per tile

static __device__ __forceinline__ unsigned short f2bf(float x) {
  unsigned u = __float_as_uint(x);
  u += 0x7fffu + ((u >> 16) & 1u);   // RNE
  return (unsigned short)(u >> 16);
}

static __device__ __forceinline__ unsigned cvtpk(float lo, float hi) {
  unsigned r;
  asm("v_cvt_pk_bf16_f32 %0, %1, %2" : "=v"(r) : "v"(lo), "v"(hi));
  return r;
}

static __device__ __forceinline__ void gload16(const void* g, void* l) {
  __builtin_amdgcn_global_load_lds(
      (const __attribute__((address_space(1))) void*)g,
      (__attribute__((address_space(3))) void*)l, 16, 0, 0);
}

static __device__ __forceinline__ f32x4 MF(bf16x8 a, bf16x8 b, f32x4 c) {
  return __builtin_amdgcn_mfma_f32_16x16x32_bf16(a, b, c, 0, 0, 0);
}

// ---------- merged prep: conv_x (bx<2048) + conv_w (2048<=bx<2304) + vt tail zero ----------
__global__ __launch_bounds__(256) void conv_kernel(
    const float* __restrict__ iq, const float* __restrict__ ik,
    const float* __restrict__ iv,
    const float* __restrict__ wq, const float* __restrict__ wk,
    const float* __restrict__ wv,
    unsigned short* __restrict__ X, unsigned short* __restrict__ Wt,
    unsigned short* __restrict__ vt) {
  const int z = blockIdx.y;
  const int bx = blockIdx.x;
  const int tid = threadIdx.x;
  if (bx < 2048) {
    const float* src = (z == 0) ? iq : (z == 1) ? ik : iv;
    const size_t off = ((size_t)bx * 256 + tid) * 8;
    const int m = (int)(off >> 10);
    unsigned short o[8];
    if (m < 4000) {
      const float4 a = *(const float4*)(src + off);
      const float4 b = *(const float4*)(src + off + 4);
      o[0]=f2bf(a.x); o[1]=f2bf(a.y); o[2]=f2bf(a.z); o[3]=f2bf(a.w);
      o[4]=f2bf(b.x); o[5]=f2bf(b.y); o[6]=f2bf(b.z); o[7]=f2bf(b.w);
    } else {
#pragma unroll
      for (int i = 0; i < 8; ++i) o[i] = 0;
    }
    uint4 pk;
    pk.x = (unsigned)o[0] | ((unsigned)o[1] << 16);
    pk.y = (unsigned)o[2] | ((unsigned)o[3] << 16);
    pk.z = (unsigned)o[4] | ((unsigned)o[5] << 16);
    pk.w = (unsigned)o[6] | ((unsigned)o[7] << 16);
    *(uint4*)(X + (size_t)z * MP * DM + off) = pk;
    return;
  }
  if (bx >= 2304) {
    if (z == 0) {
      const int idx = (bx - 2304) * 256 + tid;      // 0..8191 = bh*64 + d
      unsigned short* p = vt + (size_t)idx * LP + 496;
      const uint4 zz = {0u, 0u, 0u, 0u};
      *(uint4*)(p)     = zz;
      *(uint4*)(p + 8) = zz;
    }
    return;
  }
  const int bw = bx - 2048;
  const float* W = (z == 0) ? wq : (z == 1) ? wk : wv;
  const int k0 = (bw >> 4) * 64;
  const int n0 = (bw & 15) * 64;
  __shared__ float t[64][65];
  const int row = tid >> 2;
  const int cb  = (tid & 3) * 16;
#pragma unroll
  for (int s = 0; s < 4; ++s) {
    const float4 v = *(const float4*)(W + (size_t)(k0 + row) * DM + n0 + cb + s * 4);
    t[row][cb + s * 4 + 0] = v.x; t[row][cb + s * 4 + 1] = v.y;
    t[row][cb + s * 4 + 2] = v.z; t[row][cb + s * 4 + 3] = v.w;
  }
  __syncthreads();
  const int nr = tid >> 2;
  const int kb = (tid & 3) * 16;
#pragma unroll
  for (int s = 0; s < 2; ++s) {
    unsigned short o[8];
#pragma unroll
    for (int e = 0; e < 8; ++e) o[e] = f2bf(t[kb + s * 8 + e][nr]);
    uint4 pk;
    pk.x = (unsigned)o[0] | ((unsigned)o[1] << 16);
    pk.y = (unsigned)o[2] | ((unsigned)o[3] << 16);
    pk.z = (unsigned)o[4] | ((unsigned)o[5] << 16);
    pk.w = (unsigned)o[6] | ((unsigned)o[7] << 16);
    *(uint4*)(Wt + (size_t)z * DM * DM + (size_t)(n0 + nr) * DM + k0 + kb + s * 8) = pk;
  }
}

// ---------- QKV GEMM: 256x256 tile, BK=64, 8-phase counted-vmcnt schedule (m201) ----------
#define BAR()   __builtin_amdgcn_s_barrier()
#define LGKM0() do { asm volatile("s_waitcnt lgkmcnt(0)" ::: "memory"); \
                     __builtin_amdgcn_sched_barrier(0); } while (0)
#define P1()    __builtin_amdgcn_s_setprio(1)
#define P0()    __builtin_amdgcn_s_setprio(0)

#define QUAD(AF, BF, MB, NB)                                                   \
  _Pragma("unroll") for (int mi = 0; mi < 4; ++mi)                             \
  _Pragma("unroll") for (int ni = 0; ni < 2; ++ni) {                           \
    acc[(MB)+mi][(NB)+ni] = MF(AF[mi][0], BF[ni][0], acc[(MB)+mi][(NB)+ni]);   \
    acc[(MB)+mi][(NB)+ni] = MF(AF[mi][1], BF[ni][1], acc[(MB)+mi][(NB)+ni]); }

#define RDAF(P, MQ)                                                            \
  _Pragma("unroll") for (int mi = 0; mi < 4; ++mi) {                           \
    af[mi][0] = *(const bf16x8*)&(P)[((MQ)+mi)*1024 + kof0];                   \
    af[mi][1] = *(const bf16x8*)&(P)[((MQ)+mi)*1024 + kof1]; }

#define RDBF(P, NQ, DST)                                                       \
  _Pragma("unroll") for (int ni = 0; ni < 2; ++ni) {                           \
    DST[ni][0] = *(const bf16x8*)&(P)[((NQ)+ni)*1024 + kof0];                  \
    DST[ni][1] = *(const bf16x8*)&(P)[((NQ)+ni)*1024 + kof1]; }

__global__ __launch_bounds__(512, 2) void gemm_qkv_kernel(
    const unsigned short* __restrict__ X, const unsigned short* __restrict__ Wt,
    const float* __restrict__ bq, const float* __restrict__ bk,
    const float* __restrict__ bv,
    unsigned short* __restrict__ qo, unsigned short* __restrict__ ko,
    unsigned short* __restrict__ vo) {
  const int z = blockIdx.y;
  const unsigned short* A  = X  + (size_t)z * MP * DM;
  const unsigned short* Bw = Wt + (size_t)z * DM * DM;
  const float* bias = (z == 0) ? bq : (z == 1) ? bk : bv;
  unsigned short* out = (z == 0) ? qo : (z == 1) ? ko : vo;

  const int bx = blockIdx.x;                 // 0..63; XCD = linear%8 = bx&7
  const int xg = bx & 7, y = bx >> 3;
  const int tm = xg + 8 * (y & 1);           // 0..15
  const int tn = y >> 1;                     // 0..3

  const int tid = threadIdx.x;
  const int lane = tid & 63, wid = tid >> 6;
  const int wr = wid >> 2, wcol = wid & 3;   // 2M x 4N waves
  const int lg = lane >> 4, lr = lane & 15;

  __shared__ __attribute__((aligned(16))) unsigned short sA[32768];  // [d][half][128][64]
  __shared__ __attribute__((aligned(16))) unsigned short sB[32768];

  // staging: thread -> (rr, g) covering both halves (chunks tid, tid+512)
  const int rr = (tid >> 3) & 63;
  const int g  = tid & 7;
  const int gx = g ^ (rr & 7);               // pre-swizzled source granule
  const unsigned short* aSrc = A  + (size_t)(tm * 256 + rr) * DM + gx * 8;
  const int rb0 = rr + (rr & 32);            // B region row base (q=0)
  const unsigned short* bSrc = Bw + (size_t)(tn * 256 + rb0) * DM + gx * 8;
  const int aD = rr * 64 + g * 8;
  const int bD = rb0 * 64 + g * 8;

  auto SA_ = [&](int d, int q, int kt) {
    gload16(aSrc + (size_t)(q * 64) * DM + kt * 64,         &sA[(d*2+0)*8192 + q*4096 + aD]);
    gload16(aSrc + (size_t)(128 + q * 64) * DM + kt * 64,   &sA[(d*2+1)*8192 + q*4096 + aD]);
  };
  auto SB_ = [&](int d, int q, int kt) {
    gload16(bSrc + (size_t)(q * 32) * DM + kt * 64,         &sB[(d*2+0)*8192 + q*2048 + bD]);
    gload16(bSrc + (size_t)(128 + q * 32) * DM + kt * 64,   &sB[(d*2+1)*8192 + q*2048 + bD]);
  };

  // fragment read bases (swizzled k-granule)
  const int kof0 = ((lg)     ^ (lr & 7)) * 8;
  const int kof1 = ((4 + lg) ^ (lr & 7)) * 8;
  const unsigned short* pA0 = &sA[(0*2 + wr) * 8192 + lr * 64];
  const unsigned short* pA1 = &sA[(1*2 + wr) * 8192 + lr * 64];
  const unsigned short* pB0 = &sB[(0*2 + (wcol >> 1)) * 8192 + (wcol & 1) * 4096 + lr * 64];
  const unsigned short* pB1 = &sB[(1*2 + (wcol >> 1)) * 8192 + (wcol & 1) * 4096 + lr * 64];

  f32x4 acc[8][4];
#pragma unroll
  for (int i = 0; i < 8; ++i)
#pragma unroll
    for (int jj = 0; jj < 4; ++jj) acc[i][jj] = (f32x4){0.f, 0.f, 0.f, 0.f};

  // prologue: kt0 full (4 slots) + kt1 {Aq1,Bq0,Aq2} (3 slots); vmcnt(6) -> kt0 landed
  SA_(0, 0, 0); SB_(0, 0, 0); SA_(0, 1, 0); SB_(0, 1, 0);
  SA_(1, 0, 1); SB_(1, 0, 1); SA_(1, 1, 1);
  asm volatile("s_waitcnt vmcnt(6)" ::: "memory");
  BAR();
  __builtin_amdgcn_sched_barrier(0);

  bf16x8 af[4][2], b0[2][2], b1[2][2];

  for (int j = 0; j < 8; ++j) {
    const int k1 = 2*j + 1, k2 = 2*j + 2, k3 = 2*j + 3;
    const bool st = (j < 7);
    // ph1 (kt=2j, d0): read Aq1 + Bn0; stage Bq1-d1(k1)
    RDAF(pA0, 0); RDBF(pB0, 0, b0);
    SB_(1, 1, k1);
    BAR(); LGKM0(); P1(); QUAD(af, b0, 0, 0); P0(); BAR();
    // ph2: read Bn1(d0); stage Aq1-d0(k2)
    RDBF(pB0, 2, b1);
    if (st) SA_(0, 0, k2);
    BAR(); LGKM0(); P1(); QUAD(af, b1, 0, 2); P0(); BAR();
    // ph3: read Aq2(d0); stage Bq0-d0(k2)
    RDAF(pA0, 4);
    if (st) SB_(0, 0, k2);
    BAR(); LGKM0(); P1(); QUAD(af, b1, 4, 2); P0(); BAR();
    // ph4: regs only; stage Aq2-d0(k2); vmcnt gate for ph5-8 reads
    if (st) SA_(0, 1, k2);
    BAR(); LGKM0(); P1(); QUAD(af, b0, 4, 0); P0();
    if (st) asm volatile("s_waitcnt vmcnt(6)" ::: "memory");
    else    asm volatile("s_waitcnt vmcnt(0)" ::: "memory");
    BAR();
    // ph5 (kt=2j+1, d1): read Aq1 + Bn0; stage Bq1-d0(k2)
    RDAF(pA1, 0); RDBF(pB1, 0, b0);
    if (st) SB_(0, 1, k2);
    BAR(); LGKM0(); P1(); QUAD(af, b0, 0, 0); P0(); BAR();
    // ph6: read Bn1(d1); stage Aq1-d1(k3)
    RDBF(pB1, 2, b1);
    if (st) SA_(1, 0, k3);
    BAR(); LGKM0(); P1(); QUAD(af, b1, 0, 2); P0(); BAR();
    // ph7: read Aq2(d1); stage Bq0-d1(k3)
    RDAF(pA1, 4);
    if (st) SB_(1, 0, k3);
    BAR(); LGKM0(); P1(); QUAD(af, b1, 4, 2); P0(); BAR();
    // ph8: regs only; stage Aq2-d1(k3); vmcnt gate for next-iter ph1-4
    if (st) SA_(1, 1, k3);
    BAR(); LGKM0(); P1(); QUAD(af, b0, 4, 0); P0();
    if (st) asm volatile("s_waitcnt vmcnt(6)" ::: "memory");
    BAR();
  }

  // epilogue
  const int nb = tn * 256 + wcol * 64 + lr;
  const int hh = tn * 4 + wcol;              // single head per wave
  float bias4[4];
#pragma unroll
  for (int ni = 0; ni < 4; ++ni) bias4[ni] = bias[nb + ni * 16];

  if (z == 2) {
    // V^T: per-wave LDS transpose (all LDS dead after final barrier)
    unsigned short* T = sA + wid * 2176;     // [16][136] shorts per wave
    const int li = lane & 31, dsel = lane >> 5;
    const int m = tm * 256 + wr * 128 + li * 4;
    const unsigned batch = (unsigned)m / 500u;
    const int lrow = m - (int)batch * 500;
    const bool ok = (m < 4000);
    unsigned short* ob = out + (((size_t)batch * H_ + hh) * DK) * LP + lrow;
#pragma unroll
    for (int ni = 0; ni < 4; ++ni) {
#pragma unroll
      for (int mi = 0; mi < 8; ++mi) {
        uint2 pk;
        pk.x = (unsigned)f2bf(acc[mi][ni][0] + bias4[ni]) |
               ((unsigned)f2bf(acc[mi][ni][1] + bias4[ni]) << 16);
        pk.y = (unsigned)f2bf(acc[mi][ni][2] + bias4[ni]) |
               ((unsigned)f2bf(acc[mi][ni][3] + bias4[ni]) << 16);
        *(uint2*)&T[lr * 136 + mi * 16 + lg * 4] = pk;
      }
      asm volatile("s_waitcnt lgkmcnt(0)" ::: "memory");
      __builtin_amdgcn_sched_barrier(0);
      if (ok) {
#pragma unroll
        for (int it = 0; it < 8; ++it) {
          const int dl = it * 2 + dsel;      // 0..15
          const uint2 v = *(const uint2*)&T[dl * 136 + li * 4];
          *(uint2*)(ob + (size_t)(ni * 16 + dl) * LP) = v;
        }
      }
      asm volatile("s_waitcnt lgkmcnt(0)" ::: "memory");
      __builtin_amdgcn_sched_barrier(0);
    }
  } else {
#pragma unroll
    for (int mi = 0; mi < 8; ++mi) {
#pragma unroll
      for (int r = 0; r < 4; ++r) {
        const int m = tm * 256 + wr * 128 + mi * 16 + lg * 4 + r;
        if (m < 4000) {
          const unsigned batch = (unsigned)m / 500u;
          const int lrow = m - (int)batch * 500;
          unsigned short* op = out + (((size_t)batch * H_ + hh) * LP + lrow) * DK + lr;
#pragma unroll
          for (int ni = 0; ni < 4; ++ni)
            op[ni * 16] = f2bf(acc[mi][ni][r] + bias4[ni]);
        }
      }
    }
  }
}

// ---------- flash attention: QBLK=128, 8 waves, staged K/V, sigma-permuted QK^T,
//            P entirely in registers ----------
__global__ __launch_bounds__(512, 2) void attn_kernel(
    const unsigned short* __restrict__ q, const unsigned short* __restrict__ k,
    const unsigned short* __restrict__ vt, const float* __restrict__ rel,
    float* __restrict__ out) {
  const int id = blockIdx.x;           // XCD = id%8 = bh%8 -> per-XCD K/V L2 residency
  const int bh = id & 127, qc = id >> 7;   // qc 0..3, 128 q-rows each
  const int b = bh >> 4, h = bh & 15;
  const int tid = threadIdx.x;
  const int lane = tid & 63, wid = tid >> 6;    // 8 waves
  const int lg = lane >> 4, lr = lane & 15;

  __shared__ unsigned short kt[2][2][64][32];   // [buf][dhalf][key][d&31]
  __shared__ unsigned short vtt[2][2][64][32];  // [buf][keyhalf][d][key&31]
  __shared__ float relb[640];

  const float LOG2E = 1.44269504f;
  const float SC = 0.125f * LOG2E;
  const int rbase = qc * 128 - 12;
  for (int i = tid; i < 639; i += 512) {
    int idx = rbase + i;
    idx = idx < 0 ? 0 : (idx > 998 ? 998 : idx);
    relb[i] = rel[h * 999 + idx] * LOG2E;
  }

  const int qrow = qc * 128 + wid * 16 + lr;
  const unsigned short* qp = q + ((size_t)bh * LP + qrow) * DK + lg * 8;
  const bf16x8 qf0 = *(const bf16x8*)qp;
  const bf16x8 qf1 = *(const bf16x8*)(qp + 32);

  const int kj = tid >> 3, dcs = (tid & 7) * 8;
  const unsigned short* kgp = k + ((size_t)bh * LP + kj) * DK + dcs;
  unsigned short* kls = &kt[0][dcs >> 5][kj][dcs & 31];
  const int vd = tid >> 3, vkg = (tid & 7) * 8;
  const unsigned short* vgp = vt + ((size_t)bh * DK + vd) * LP + vkg;
  unsigned short* vls = &vtt[0][vkg >> 5][vd][vkg & 31];

  const int sig0 = 8 * (lr >> 2) + (lr & 3);   // sigma base
  const int qin = wid * 16 + lr;               // 0..127

  f32x4 o[4];
#pragma unroll
  for (int d = 0; d < 4; ++d) o[d] = (f32x4){0.f, 0.f, 0.f, 0.f};
  float mrun = -1e30f, lrun = 0.f;

  uint4 ka0 = *(const uint4*)(kgp);
  uint4 va0 = *(const uint4*)(vgp);

  for (int t = 0; t < NT; ++t) {
    const int buf = t & 1;
    *(uint4*)(kls + buf * 4096) = ka0;
    *(uint4*)(vls + buf * 4096) = va0;
    __syncthreads();

    if (t < NT - 1) {
      ka0 = *(const uint4*)(kgp + (size_t)(t + 1) * 64 * DK);
      va0 = *(const uint4*)(vgp + (t + 1) * 64);
    }

    f32x4 s[2][2];
#pragma unroll
    for (int kc = 0; kc < 2; ++kc)
#pragma unroll
      for (int hf = 0; hf < 2; ++hf) {
        const int sg = kc * 32 + hf * 4 + sig0;
        const bf16x8 a0 = *(const bf16x8*)&kt[buf][0][sg][lg * 8];
        const bf16x8 a1 = *(const bf16x8*)&kt[buf][1][sg][lg * 8];
        f32x4 ss = (f32x4){0.f, 0.f, 0.f, 0.f};
        ss = __builtin_amdgcn_mfma_f32_16x16x32_bf16(a0, qf0, ss, 0, 0, 0);
        ss = __builtin_amdgcn_mfma_f32_16x16x32_bf16(a1, qf1, ss, 0, 0, 0);
        s[kc][hf] = ss;
      }

    float sc[2][2][4];
#pragma unroll
    for (int kc = 0; kc < 2; ++kc)
#pragma unroll
      for (int hf = 0; hf < 2; ++hf) {
        const int bidx = qin - (t * 64 + kc * 32 + 8 * lg + 4 * hf) + 511;
#pragma unroll
        for (int r = 0; r < 4; ++r)
          sc[kc][hf][r] = s[kc][hf][r] * SC + relb[bidx - r];
      }
    if (t == NT - 1) {
#pragma unroll
      for (int hf = 0; hf < 2; ++hf)
#pragma unroll
        for (int r = 0; r < 4; ++r)
          if (8 * lg + 4 * hf + r >= 20) sc[1][hf][r] = -1e30f;
    }

    float m0 = fmaxf(fmaxf(sc[0][0][0], sc[0][0][1]), fmaxf(sc[0][0][2], sc[0][0][3]));
    float m1 = fmaxf(fmaxf(sc[0][1][0], sc[0][1][1]), fmaxf(sc[0][1][2], sc[0][1][3]));
    float m2 = fmaxf(fmaxf(sc[1][0][0], sc[1][0][1]), fmaxf(sc[1][0][2], sc[1][0][3]));
    float m3 = fmaxf(fmaxf(sc[1][1][0], sc[1][1][1]), fmaxf(sc[1][1][2], sc[1][1][3]));
    const float mloc = fmaxf(fmaxf(m0, m1), fmaxf(m2, m3));
    if (!__all(mloc - mrun <= 11.5f)) {
      float mx = fmaxf(mloc, mrun);
      mx = fmaxf(mx, __shfl_xor(mx, 16));
      mx = fmaxf(mx, __shfl_xor(mx, 32));
      const float alpha = exp2f(mrun - mx);
      mrun = mx;
      lrun *= alpha;
#pragma unroll
      for (int d = 0; d < 4; ++d) {
        o[d][0] *= alpha; o[d][1] *= alpha; o[d][2] *= alpha; o[d][3] *= alpha;
      }
    }

    float rs = 0.f;
    unsigned pw[2][4];
#pragma unroll
    for (int kc = 0; kc < 2; ++kc)
#pragma unroll
      for (int hf = 0; hf < 2; ++hf) {
        float p0 = exp2f(sc[kc][hf][0] - mrun);
        float p1 = exp2f(sc[kc][hf][1] - mrun);
        float p2 = exp2f(sc[kc][hf][2] - mrun);
        float p3 = exp2f(sc[kc][hf][3] - mrun);
        rs += (p0 + p1) + (p2 + p3);
        pw[kc][hf * 2 + 0] = cvtpk(p0, p1);
        pw[kc][hf * 2 + 1] = cvtpk(p2, p3);
      }
    rs += __shfl_xor(rs, 16);
    rs += __shfl_xor(rs, 32);
    lrun += rs;

#pragma unroll
    for (int kc = 0; kc < 2; ++kc) {
      union { uint4v u; bf16x8 v; } cv;
      cv.u = (uint4v){pw[kc][0], pw[kc][1], pw[kc][2], pw[kc][3]};
      const bf16x8 pf = cv.v;
#pragma unroll
      for (int db = 0; db < 4; ++db) {
        const bf16x8 vf = *(const bf16x8*)&vtt[buf][kc][db * 16 + lr][lg * 8];
        o[db] = __builtin_amdgcn_mfma_f32_16x16x32_bf16(vf, pf, o[db], 0, 0, 0);
      }
    }
  }

  if (qrow < L_) {
    const float inv = 1.0f / lrun;
    float* op = out + ((size_t)b * L_ + qrow) * DM + h * DK + lg * 4;
#pragma unroll
    for (int db = 0; db < 4; ++db) {
      float4 v;
      v.x = o[db][0] * inv; v.y = o[db][1] * inv;
      v.z = o[db][2] * inv; v.w = o[db][3] * inv;
      *(float4*)(op + db * 16) = v;
    }
  }
}

extern "C" void kernel_launch(void* const* d_in, const int* in_sizes, int n_in,
                              void* d_out, int out_size, void* d_ws, size_t ws_size,
                              hipStream_t stream) {
  const float* iq  = (const float*)d_in[0];
  const float* ik  = (const float*)d_in[1];
  const float* iv  = (const float*)d_in[2];
  const float* wq  = (const float*)d_in[3];
  const float* bq  = (const float*)d_in[4];
  const float* wk  = (const float*)d_in[5];
  const float* bk  = (const float*)d_in[6];
  const float* wv  = (const float*)d_in[7];
  const float* bv  = (const float*)d_in[8];
  const float* rel = (const float*)d_in[9];
  float* out = (float*)d_out;

  char* w = (char*)d_ws;
  unsigned short* X   = (unsigned short*)(w);                 // [3][4096][1024] bf16
  unsigned short* Wt  = (unsigned short*)(w + 25165824);      // [3][1024][1024] bf16 (n,k)
  unsigned short* qb  = (unsigned short*)(w + 31457280);      // [128][512][64] bf16
  unsigned short* kb  = (unsigned short*)(w + 39845888);
  unsigned short* vtb = (unsigned short*)(w + 48234496);      // [128][64][512] bf16 (V^T)

  conv_kernel<<<dim3(2336, 3), 256, 0, stream>>>(iq, ik, iv, wq, wk, wv, X, Wt, vtb);
  gemm_qkv_kernel<<<dim3(64, 3), 512, 0, stream>>>(X, Wt, bq, bk, bv, qb, kb, vtb);
  attn_kernel<<<512, 512, 0, stream>>>(qb, kb, vtb, rel, out);
}

// Round 17
// 76.710 us; speedup vs baseline: 2.9034x; 1.0139x over previous
//
#include <hip/hip_runtime.h>

typedef short bf16x8 __attribute__((ext_vector_type(8)));
typedef float f32x4 __attribute__((ext_vector_type(4)));
typedef unsigned uint4v __attribute__((ext_vector_type(4)));

#define B_    8
#define L_    500
#define LP    512
#define H_    16
#define DK    64
#define DM    1024
#define MP    4096
#define NT    8      // attn: 512 / 64 keys per tile

static __device__ __forceinline__ unsigned short f2bf(float x) {
  unsigned u = __float_as_uint(x);
  u += 0x7fffu + ((u >> 16) & 1u);   // RNE
  return (unsigned short)(u >> 16);
}

static __device__ __forceinline__ unsigned cvtpk(float lo, float hi) {
  unsigned r;
  asm("v_cvt_pk_bf16_f32 %0, %1, %2" : "=v"(r) : "v"(lo), "v"(hi));
  return r;
}

static __device__ __forceinline__ void gload16(const void* g, void* l) {
  __builtin_amdgcn_global_load_lds(
      (const __attribute__((address_space(1))) void*)g,
      (__attribute__((address_space(3))) void*)l, 16, 0, 0);
}

static __device__ __forceinline__ f32x4 MF(bf16x8 a, bf16x8 b, f32x4 c) {
  return __builtin_amdgcn_mfma_f32_16x16x32_bf16(a, b, c, 0, 0, 0);
}

// ---------- merged prep: conv_x (bx<2048) + conv_w (2048<=bx<2304) + vt tail zero ----------
__global__ __launch_bounds__(256) void conv_kernel(
    const float* __restrict__ iq, const float* __restrict__ ik,
    const float* __restrict__ iv,
    const float* __restrict__ wq, const float* __restrict__ wk,
    const float* __restrict__ wv,
    unsigned short* __restrict__ X, unsigned short* __restrict__ Wt,
    unsigned short* __restrict__ vt) {
  const int z = blockIdx.y;
  const int bx = blockIdx.x;
  const int tid = threadIdx.x;
  if (bx < 2048) {
    const float* src = (z == 0) ? iq : (z == 1) ? ik : iv;
    const size_t off = ((size_t)bx * 256 + tid) * 8;
    const int m = (int)(off >> 10);
    unsigned short o[8];
    if (m < 4000) {
      const float4 a = *(const float4*)(src + off);
      const float4 b = *(const float4*)(src + off + 4);
      o[0]=f2bf(a.x); o[1]=f2bf(a.y); o[2]=f2bf(a.z); o[3]=f2bf(a.w);
      o[4]=f2bf(b.x); o[5]=f2bf(b.y); o[6]=f2bf(b.z); o[7]=f2bf(b.w);
    } else {
#pragma unroll
      for (int i = 0; i < 8; ++i) o[i] = 0;
    }
    uint4 pk;
    pk.x = (unsigned)o[0] | ((unsigned)o[1] << 16);
    pk.y = (unsigned)o[2] | ((unsigned)o[3] << 16);
    pk.z = (unsigned)o[4] | ((unsigned)o[5] << 16);
    pk.w = (unsigned)o[6] | ((unsigned)o[7] << 16);
    *(uint4*)(X + (size_t)z * MP * DM + off) = pk;
    return;
  }
  if (bx >= 2304) {
    if (z == 0) {
      const int idx = (bx - 2304) * 256 + tid;      // 0..8191 = bh*64 + d
      unsigned short* p = vt + (size_t)idx * LP + 496;
      const uint4 zz = {0u, 0u, 0u, 0u};
      *(uint4*)(p)     = zz;
      *(uint4*)(p + 8) = zz;
    }
    return;
  }
  const int bw = bx - 2048;
  const float* W = (z == 0) ? wq : (z == 1) ? wk : wv;
  const int k0 = (bw >> 4) * 64;
  const int n0 = (bw & 15) * 64;
  __shared__ float t[64][65];
  const int row = tid >> 2;
  const int cb  = (tid & 3) * 16;
#pragma unroll
  for (int s = 0; s < 4; ++s) {
    const float4 v = *(const float4*)(W + (size_t)(k0 + row) * DM + n0 + cb + s * 4);
    t[row][cb + s * 4 + 0] = v.x; t[row][cb + s * 4 + 1] = v.y;
    t[row][cb + s * 4 + 2] = v.z; t[row][cb + s * 4 + 3] = v.w;
  }
  __syncthreads();
  const int nr = tid >> 2;
  const int kb = (tid & 3) * 16;
#pragma unroll
  for (int s = 0; s < 2; ++s) {
    unsigned short o[8];
#pragma unroll
    for (int e = 0; e < 8; ++e) o[e] = f2bf(t[kb + s * 8 + e][nr]);
    uint4 pk;
    pk.x = (unsigned)o[0] | ((unsigned)o[1] << 16);
    pk.y = (unsigned)o[2] | ((unsigned)o[3] << 16);
    pk.z = (unsigned)o[4] | ((unsigned)o[5] << 16);
    pk.w = (unsigned)o[6] | ((unsigned)o[7] << 16);
    *(uint4*)(Wt + (size_t)z * DM * DM + (size_t)(n0 + nr) * DM + k0 + kb + s * 8) = pk;
  }
}

// ---------- QKV GEMM: 256x256 tile, BK=64, 4-phase counted-vmcnt schedule ----------
#define BAR()   __builtin_amdgcn_s_barrier()
#define LGKM0() do { asm volatile("s_waitcnt lgkmcnt(0)" ::: "memory"); \
                     __builtin_amdgcn_sched_barrier(0); } while (0)
#define P1()    __builtin_amdgcn_s_setprio(1)
#define P0()    __builtin_amdgcn_s_setprio(0)

#define QUAD(AF, BF, MB, NB)                                                   \
  _Pragma("unroll") for (int mi = 0; mi < 4; ++mi)                             \
  _Pragma("unroll") for (int ni = 0; ni < 2; ++ni) {                           \
    acc[(MB)+mi][(NB)+ni] = MF(AF[mi][0], BF[ni][0], acc[(MB)+mi][(NB)+ni]);   \
    acc[(MB)+mi][(NB)+ni] = MF(AF[mi][1], BF[ni][1], acc[(MB)+mi][(NB)+ni]); }

#define RDAF(P, MQ)                                                            \
  _Pragma("unroll") for (int mi = 0; mi < 4; ++mi) {                           \
    af[mi][0] = *(const bf16x8*)&(P)[((MQ)+mi)*1024 + kof0];                   \
    af[mi][1] = *(const bf16x8*)&(P)[((MQ)+mi)*1024 + kof1]; }

#define RDBF(P, NQ, DST)                                                       \
  _Pragma("unroll") for (int ni = 0; ni < 2; ++ni) {                           \
    DST[ni][0] = *(const bf16x8*)&(P)[((NQ)+ni)*1024 + kof0];                  \
    DST[ni][1] = *(const bf16x8*)&(P)[((NQ)+ni)*1024 + kof1]; }

__global__ __launch_bounds__(512, 2) void gemm_qkv_kernel(
    const unsigned short* __restrict__ X, const unsigned short* __restrict__ Wt,
    const float* __restrict__ bq, const float* __restrict__ bk,
    const float* __restrict__ bv,
    unsigned short* __restrict__ qo, unsigned short* __restrict__ ko,
    unsigned short* __restrict__ vo) {
  const int z = blockIdx.y;
  const unsigned short* A  = X  + (size_t)z * MP * DM;
  const unsigned short* Bw = Wt + (size_t)z * DM * DM;
  const float* bias = (z == 0) ? bq : (z == 1) ? bk : bv;
  unsigned short* out = (z == 0) ? qo : (z == 1) ? ko : vo;

  const int bx = blockIdx.x;                 // 0..63; XCD = bx&7
  const int xg = bx & 7, y = bx >> 3;
  const int tm = xg + 8 * (y & 1);           // 0..15
  const int tn = y >> 1;                     // 0..3

  const int tid = threadIdx.x;
  const int lane = tid & 63, wid = tid >> 6;
  const int wr = wid >> 2, wcol = wid & 3;   // 2M x 4N waves
  const int lg = lane >> 4, lr = lane & 15;

  __shared__ __attribute__((aligned(16))) unsigned short sA[32768];  // [d][half][128][64]
  __shared__ __attribute__((aligned(16))) unsigned short sB[32768];

  const int rr = (tid >> 3) & 63;
  const int g  = tid & 7;
  const int gx = g ^ (rr & 7);               // pre-swizzled source granule
  const unsigned short* aSrc = A  + (size_t)(tm * 256 + rr) * DM + gx * 8;
  const int rb0 = rr + (rr & 32);            // B region row base (q=0)
  const unsigned short* bSrc = Bw + (size_t)(tn * 256 + rb0) * DM + gx * 8;
  const int aD = rr * 64 + g * 8;
  const int bD = rb0 * 64 + g * 8;

  auto SA_ = [&](int d, int q, int kt) {
    gload16(aSrc + (size_t)(q * 64) * DM + kt * 64,         &sA[(d*2+0)*8192 + q*4096 + aD]);
    gload16(aSrc + (size_t)(128 + q * 64) * DM + kt * 64,   &sA[(d*2+1)*8192 + q*4096 + aD]);
  };
  auto SB_ = [&](int d, int q, int kt) {
    gload16(bSrc + (size_t)(q * 32) * DM + kt * 64,         &sB[(d*2+0)*8192 + q*2048 + bD]);
    gload16(bSrc + (size_t)(128 + q * 32) * DM + kt * 64,   &sB[(d*2+1)*8192 + q*2048 + bD]);
  };

  const int kof0 = ((lg)     ^ (lr & 7)) * 8;
  const int kof1 = ((4 + lg) ^ (lr & 7)) * 8;
  const unsigned short* pA0 = &sA[(0*2 + wr) * 8192 + lr * 64];
  const unsigned short* pA1 = &sA[(1*2 + wr) * 8192 + lr * 64];
  const unsigned short* pB0 = &sB[(0*2 + (wcol >> 1)) * 8192 + (wcol & 1) * 4096 + lr * 64];
  const unsigned short* pB1 = &sB[(1*2 + (wcol >> 1)) * 8192 + (wcol & 1) * 4096 + lr * 64];

  f32x4 acc[8][4];
#pragma unroll
  for (int i = 0; i < 8; ++i)
#pragma unroll
    for (int jj = 0; jj < 4; ++jj) acc[i][jj] = (f32x4){0.f, 0.f, 0.f, 0.f};

  // prologue: kt0 full (4 slots) + kt1 {Aq1,Bq0,Aq2} (3 slots); vmcnt(6) -> kt0 landed
  SA_(0, 0, 0); SB_(0, 0, 0); SA_(0, 1, 0); SB_(0, 1, 0);
  SA_(1, 0, 1); SB_(1, 0, 1); SA_(1, 1, 1);
  asm volatile("s_waitcnt vmcnt(6)" ::: "memory");
  BAR();
  __builtin_amdgcn_sched_barrier(0);

  bf16x8 af[4][2], b0[2][2], b1[2][2];

  for (int j = 0; j < 8; ++j) {
    const int k1 = 2*j + 1, k2 = 2*j + 2, k3 = 2*j + 3;
    const bool st = (j < 7);
    // phA (kt=2j, d0): read Aq1 + all B; stage Bq1-d1(k1), Aq1-d0(k2); 32 MFMA
    RDAF(pA0, 0); RDBF(pB0, 0, b0); RDBF(pB0, 2, b1);
    SB_(1, 1, k1);
    if (st) SA_(0, 0, k2);
    BAR(); LGKM0(); P1(); QUAD(af, b0, 0, 0); QUAD(af, b1, 0, 2); P0(); BAR();
    // phB: read Aq2(d0); stage Bq0-d0(k2), Aq2-d0(k2); 32 MFMA; vmcnt gate for d1
    RDAF(pA0, 4);
    if (st) { SB_(0, 0, k2); SA_(0, 1, k2); }
    BAR(); LGKM0(); P1(); QUAD(af, b1, 4, 2); QUAD(af, b0, 4, 0); P0();
    if (st) asm volatile("s_waitcnt vmcnt(6)" ::: "memory");
    else    asm volatile("s_waitcnt vmcnt(0)" ::: "memory");
    BAR();
    // phC (kt=2j+1, d1): read Aq1 + all B; stage Bq1-d0(k2), Aq1-d1(k3); 32 MFMA
    RDAF(pA1, 0); RDBF(pB1, 0, b0); RDBF(pB1, 2, b1);
    if (st) { SB_(0, 1, k2); SA_(1, 0, k3); }
    BAR(); LGKM0(); P1(); QUAD(af, b0, 0, 0); QUAD(af, b1, 0, 2); P0(); BAR();
    // phD: read Aq2(d1); stage Bq0-d1(k3), Aq2-d1(k3); 32 MFMA; vmcnt gate for next d0
    RDAF(pA1, 4);
    if (st) { SB_(1, 0, k3); SA_(1, 1, k3); }
    BAR(); LGKM0(); P1(); QUAD(af, b1, 4, 2); QUAD(af, b0, 4, 0); P0();
    if (st) asm volatile("s_waitcnt vmcnt(6)" ::: "memory");
    BAR();
  }

  // epilogue
  const int nb = tn * 256 + wcol * 64 + lr;
  const int hh = tn * 4 + wcol;              // single head per wave
  float bias4[4];
#pragma unroll
  for (int ni = 0; ni < 4; ++ni) bias4[ni] = bias[nb + ni * 16];

  if (z == 2) {
    unsigned short* T = sA + wid * 2176;     // [16][136] shorts per wave
    const int li = lane & 31, dsel = lane >> 5;
    const int m = tm * 256 + wr * 128 + li * 4;
    const unsigned batch = (unsigned)m / 500u;
    const int lrow = m - (int)batch * 500;
    const bool ok = (m < 4000);
    unsigned short* ob = out + (((size_t)batch * H_ + hh) * DK) * LP + lrow;
#pragma unroll
    for (int ni = 0; ni < 4; ++ni) {
#pragma unroll
      for (int mi = 0; mi < 8; ++mi) {
        uint2 pk;
        pk.x = (unsigned)f2bf(acc[mi][ni][0] + bias4[ni]) |
               ((unsigned)f2bf(acc[mi][ni][1] + bias4[ni]) << 16);
        pk.y = (unsigned)f2bf(acc[mi][ni][2] + bias4[ni]) |
               ((unsigned)f2bf(acc[mi][ni][3] + bias4[ni]) << 16);
        *(uint2*)&T[lr * 136 + mi * 16 + lg * 4] = pk;
      }
      asm volatile("s_waitcnt lgkmcnt(0)" ::: "memory");
      __builtin_amdgcn_sched_barrier(0);
      if (ok) {
#pragma unroll
        for (int it = 0; it < 8; ++it) {
          const int dl = it * 2 + dsel;      // 0..15
          const uint2 v = *(const uint2*)&T[dl * 136 + li * 4];
          *(uint2*)(ob + (size_t)(ni * 16 + dl) * LP) = v;
        }
      }
      asm volatile("s_waitcnt lgkmcnt(0)" ::: "memory");
      __builtin_amdgcn_sched_barrier(0);
    }
  } else {
#pragma unroll
    for (int mi = 0; mi < 8; ++mi) {
#pragma unroll
      for (int r = 0; r < 4; ++r) {
        const int m = tm * 256 + wr * 128 + mi * 16 + lg * 4 + r;
        if (m < 4000) {
          const unsigned batch = (unsigned)m / 500u;
          const int lrow = m - (int)batch * 500;
          unsigned short* op = out + (((size_t)batch * H_ + hh) * LP + lrow) * DK + lr;
#pragma unroll
          for (int ni = 0; ni < 4; ++ni)
            op[ni * 16] = f2bf(acc[mi][ni][r] + bias4[ni]);
        }
      }
    }
  }
}

// ---------- flash attention: QBLK=128, 8 waves, staged K/V, sigma-permuted QK^T,
//            P entirely in registers ----------
__global__ __launch_bounds__(512, 2) void attn_kernel(
    const unsigned short* __restrict__ q, const unsigned short* __restrict__ k,
    const unsigned short* __restrict__ vt, const float* __restrict__ rel,
    float* __restrict__ out) {
  const int id = blockIdx.x;           // XCD = id%8 = bh%8 -> per-XCD K/V L2 residency
  const int bh = id & 127, qc = id >> 7;   // qc 0..3, 128 q-rows each
  const int b = bh >> 4, h = bh & 15;
  const int tid = threadIdx.x;
  const int lane = tid & 63, wid = tid >> 6;    // 8 waves
  const int lg = lane >> 4, lr = lane & 15;

  __shared__ unsigned short kt[2][2][64][32];   // [buf][dhalf][key][d&31]
  __shared__ unsigned short vtt[2][2][64][32];  // [buf][keyhalf][d][key&31]
  __shared__ float relb[640];

  const float LOG2E = 1.44269504f;
  const float SC = 0.125f * LOG2E;
  const int rbase = qc * 128 - 12;
  for (int i = tid; i < 639; i += 512) {
    int idx = rbase + i;
    idx = idx < 0 ? 0 : (idx > 998 ? 998 : idx);
    relb[i] = rel[h * 999 + idx] * LOG2E;
  }

  const int qrow = qc * 128 + wid * 16 + lr;
  const unsigned short* qp = q + ((size_t)bh * LP + qrow) * DK + lg * 8;
  const bf16x8 qf0 = *(const bf16x8*)qp;
  const bf16x8 qf1 = *(const bf16x8*)(qp + 32);

  const int kj = tid >> 3, dcs = (tid & 7) * 8;
  const unsigned short* kgp = k + ((size_t)bh * LP + kj) * DK + dcs;
  unsigned short* kls = &kt[0][dcs >> 5][kj][dcs & 31];
  const int vd = tid >> 3, vkg = (tid & 7) * 8;
  const unsigned short* vgp = vt + ((size_t)bh * DK + vd) * LP + vkg;
  unsigned short* vls = &vtt[0][vkg >> 5][vd][vkg & 31];

  const int sig0 = 8 * (lr >> 2) + (lr & 3);   // sigma base
  const int qin = wid * 16 + lr;               // 0..127

  f32x4 o[4];
#pragma unroll
  for (int d = 0; d < 4; ++d) o[d] = (f32x4){0.f, 0.f, 0.f, 0.f};
  float mrun = -1e30f, lrun = 0.f;

  uint4 ka0 = *(const uint4*)(kgp);
  uint4 va0 = *(const uint4*)(vgp);

  for (int t = 0; t < NT; ++t) {
    const int buf = t & 1;
    *(uint4*)(kls + buf * 4096) = ka0;
    *(uint4*)(vls + buf * 4096) = va0;
    __syncthreads();

    if (t < NT - 1) {
      ka0 = *(const uint4*)(kgp + (size_t)(t + 1) * 64 * DK);
      va0 = *(const uint4*)(vgp + (t + 1) * 64);
    }

    f32x4 s[2][2];
#pragma unroll
    for (int kc = 0; kc < 2; ++kc)
#pragma unroll
      for (int hf = 0; hf < 2; ++hf) {
        const int sg = kc * 32 + hf * 4 + sig0;
        const bf16x8 a0 = *(const bf16x8*)&kt[buf][0][sg][lg * 8];
        const bf16x8 a1 = *(const bf16x8*)&kt[buf][1][sg][lg * 8];
        f32x4 ss = (f32x4){0.f, 0.f, 0.f, 0.f};
        ss = __builtin_amdgcn_mfma_f32_16x16x32_bf16(a0, qf0, ss, 0, 0, 0);
        ss = __builtin_amdgcn_mfma_f32_16x16x32_bf16(a1, qf1, ss, 0, 0, 0);
        s[kc][hf] = ss;
      }

    float sc[2][2][4];
#pragma unroll
    for (int kc = 0; kc < 2; ++kc)
#pragma unroll
      for (int hf = 0; hf < 2; ++hf) {
        const int bidx = qin - (t * 64 + kc * 32 + 8 * lg + 4 * hf) + 511;
#pragma unroll
        for (int r = 0; r < 4; ++r)
          sc[kc][hf][r] = s[kc][hf][r] * SC + relb[bidx - r];
      }
    if (t == NT - 1) {
#pragma unroll
      for (int hf = 0; hf < 2; ++hf)
#pragma unroll
        for (int r = 0; r < 4; ++r)
          if (8 * lg + 4 * hf + r >= 20) sc[1][hf][r] = -1e30f;
    }

    float m0 = fmaxf(fmaxf(sc[0][0][0], sc[0][0][1]), fmaxf(sc[0][0][2], sc[0][0][3]));
    float m1 = fmaxf(fmaxf(sc[0][1][0], sc[0][1][1]), fmaxf(sc[0][1][2], sc[0][1][3]));
    float m2 = fmaxf(fmaxf(sc[1][0][0], sc[1][0][1]), fmaxf(sc[1][0][2], sc[1][0][3]));
    float m3 = fmaxf(fmaxf(sc[1][1][0], sc[1][1][1]), fmaxf(sc[1][1][2], sc[1][1][3]));
    const float mloc = fmaxf(fmaxf(m0, m1), fmaxf(m2, m3));
    if (!__all(mloc - mrun <= 11.5f)) {
      float mx = fmaxf(mloc, mrun);
      mx = fmaxf(mx, __shfl_xor(mx, 16));
      mx = fmaxf(mx, __shfl_xor(mx, 32));
      const float alpha = exp2f(mrun - mx);
      mrun = mx;
      lrun *= alpha;
#pragma unroll
      for (int d = 0; d < 4; ++d) {
        o[d][0] *= alpha; o[d][1] *= alpha; o[d][2] *= alpha; o[d][3] *= alpha;
      }
    }

    float rs = 0.f;
    unsigned pw[2][4];
#pragma unroll
    for (int kc = 0; kc < 2; ++kc)
#pragma unroll
      for (int hf = 0; hf < 2; ++hf) {
        float p0 = exp2f(sc[kc][hf][0] - mrun);
        float p1 = exp2f(sc[kc][hf][1] - mrun);
        float p2 = exp2f(sc[kc][hf][2] - mrun);
        float p3 = exp2f(sc[kc][hf][3] - mrun);
        rs += (p0 + p1) + (p2 + p3);
        pw[kc][hf * 2 + 0] = cvtpk(p0, p1);
        pw[kc][hf * 2 + 1] = cvtpk(p2, p3);
      }
    rs += __shfl_xor(rs, 16);
    rs += __shfl_xor(rs, 32);
    lrun += rs;

#pragma unroll
    for (int kc = 0; kc < 2; ++kc) {
      union { uint4v u; bf16x8 v; } cv;
      cv.u = (uint4v){pw[kc][0], pw[kc][1], pw[kc][2], pw[kc][3]};
      const bf16x8 pf = cv.v;
#pragma unroll
      for (int db = 0; db < 4; ++db) {
        const bf16x8 vf = *(const bf16x8*)&vtt[buf][kc][db * 16 + lr][lg * 8];
        o[db] = __builtin_amdgcn_mfma_f32_16x16x32_bf16(vf, pf, o[db], 0, 0, 0);
      }
    }
  }

  if (qrow < L_) {
    const float inv = 1.0f / lrun;
    float* op = out + ((size_t)b * L_ + qrow) * DM + h * DK + lg * 4;
#pragma unroll
    for (int db = 0; db < 4; ++db) {
      float4 v;
      v.x = o[db][0] * inv; v.y = o[db][1] * inv;
      v.z = o[db][2] * inv; v.w = o[db][3] * inv;
      *(float4*)(op + db * 16) = v;
    }
  }
}

extern "C" void kernel_launch(void* const* d_in, const int* in_sizes, int n_in,
                              void* d_out, int out_size, void* d_ws, size_t ws_size,
                              hipStream_t stream) {
  const float* iq  = (const float*)d_in[0];
  const float* ik  = (const float*)d_in[1];
  const float* iv  = (const float*)d_in[2];
  const float* wq  = (const float*)d_in[3];
  const float* bq  = (const float*)d_in[4];
  const float* wk  = (const float*)d_in[5];
  const float* bk  = (const float*)d_in[6];
  const float* wv  = (const float*)d_in[7];
  const float* bv  = (const float*)d_in[8];
  const float* rel = (const float*)d_in[9];
  float* out = (float*)d_out;

  char* w = (char*)d_ws;
  unsigned short* X   = (unsigned short*)(w);                 // [3][4096][1024] bf16
  unsigned short* Wt  = (unsigned short*)(w + 25165824);      // [3][1024][1024] bf16 (n,k)
  unsigned short* qb  = (unsigned short*)(w + 31457280);      // [128][512][64] bf16
  unsigned short* kb  = (unsigned short*)(w + 39845888);
  unsigned short* vtb = (unsigned short*)(w + 48234496);      // [128][64][512] bf16 (V^T)

  conv_kernel<<<dim3(2336, 3), 256, 0, stream>>>(iq, ik, iv, wq, wk, wv, X, Wt, vtb);
  gemm_qkv_kernel<<<dim3(64, 3), 512, 0, stream>>>(X, Wt, bq, bk, bv, qb, kb, vtb);
  attn_kernel<<<512, 512, 0, stream>>>(qb, kb, vtb, rel, out);
}